// Round 6
// baseline (350.239 us; speedup 1.0000x reference)
//
#include <hip/hip_runtime.h>
#include <hip/hip_bf16.h>

// C[M,N] = A[M,K] @ W[N,K]^T ; M=32768, N=K=2048. fp32 in/out.
// R6: 256x256-tile 8-wave 8-phase GEMM with REGISTER-NEUTRAL 1-phase lookahead:
// each phase = [lgkm(0) | 16 MFMA(Q) | ds_read frags for NEXT phase into the
// SAME af/bfr regs (dead after MFMA) | stage | vm-gate | ONE s_barrier].
// LDS latency hides across the barrier; lgkm(0) at phase entry is ~free.
// vmcnt ledger (per wave; stage A(t+1) = 4 loads @P0-end, B halves 2 each):
//   in-flight at P0 start: [B(t+1)x4]
//   P0:+4 A(t+1) ->8   P1:+0 ->8   P2:+2 B0(t+2) ->10, GATE vmcnt(2)
//     (retires B(t+1)x4 + A(t+1)x4 -> published for P3-end reads of buf1)
//   P3:+2 B1(t+2) ->4  P4:+4 A(t+2) ->8  P5:+0 ->8  P6:+2 B0(t+3) ->10,
//     GATE vmcnt(2) (retires B(t+2)x4 + A(t+2)x4 -> P7-end reads of buf0)
//   P7:+2 B1(t+3) ->4  (invariant).  Peel iter: gate vmcnt(0) at its P2.
// Write-after-read (1 barrier/phase): every stage is >=2 barriers after the
// last ds_read of its region (checked per region A0/A1/B0/B1).

typedef __attribute__((ext_vector_type(8))) short bf16x8;
typedef __attribute__((ext_vector_type(4))) float f32x4;

#define M_DIM 32768
#define N_DIM 2048
#define K_DIM 2048
#define BM 256
#define BN 256
#define BK 64
#define NT (K_DIM / BK)              // 32
#define NBN (N_DIM / BN)             // 8
#define NWG ((M_DIM / BM) * NBN)     // 1024

typedef __attribute__((address_space(3))) char lds_char;
typedef __attribute__((address_space(1))) char glb_char;

__device__ __forceinline__ unsigned short f2bf(float f) {
    __bf16 b = (__bf16)f;   // RNE
    return __builtin_bit_cast(unsigned short, b);
}

// ---------------- fp32 -> bf16 convert (memory-bound, grid-stride) ----------
__global__ __launch_bounds__(256)
void cvt_f32_bf16(const float* __restrict__ src, ushort* __restrict__ dst, int n8) {
    const float4* s4 = (const float4*)src;
    int idx = blockIdx.x * blockDim.x + threadIdx.x;
    int stride = gridDim.x * blockDim.x;
    for (int i = idx; i < n8; i += stride) {
        float4 a = s4[2 * (size_t)i];
        float4 b = s4[2 * (size_t)i + 1];
        ushort r[8] = {f2bf(a.x), f2bf(a.y), f2bf(a.z), f2bf(a.w),
                       f2bf(b.x), f2bf(b.y), f2bf(b.z), f2bf(b.w)};
        *reinterpret_cast<uint4*>(dst + 8 * (size_t)i) =
            *reinterpret_cast<const uint4*>(r);
    }
}

// ---------------- 256^2 8-wave lookahead-pipelined bf16 GEMM ----------------
__global__ __launch_bounds__(512, 2)
void agmm_8phase(const ushort* __restrict__ A, const ushort* __restrict__ W,
                 float* __restrict__ C) {
    // sA[buf]: buf*32768 ; sB[buf]: 65536 + buf*32768 (256r x 64c bf16, 128B rows)
    __shared__ __attribute__((aligned(16))) char sm[131072];

    const int tid  = threadIdx.x;
    const int lane = tid & 63;
    const int w    = tid >> 6;      // 0..7
    const int wm   = w >> 2;        // 0..1 -> 128-row half of A tile
    const int wn   = w & 3;         // 0..3 -> 64-col slice of B tile

    const int bid = blockIdx.x;
    const int swz = (bid & 7) * (NWG / 8) + (bid >> 3);  // bijective (NWG%8==0)
    const int bm  = swz >> 3;            // 0..127
    const int bn  = swz & (NBN - 1);     // 0..7

    // staging source pre-swizzle (linear LDS dest; read applies same XOR)
    const int lsub = lane >> 3;                       // row&7 at dest
    const int scol = ((lane & 7) ^ lsub) << 3;        // pre-swizzled col elems

    const ushort* Abase = A + (size_t)bm * BM * K_DIM + scol;
    const ushort* Wbase = W + (size_t)bn * BN * K_DIM + scol;

    const int lrow = lane & 15;
    const int fxor = (lrow & 7) << 4;
    const int kcb0 = (lane >> 4) << 4;    // 0,16,32,48 byte k-offset

    // fragment read bases (loop-invariant)
    const int ab0 = (wm * 128 + lrow) * 128;           // buf0 A
    const int ab1 = 32768 + ab0;                       // buf1 A
    const int bb0 = 65536 + (wn * 64 + lrow) * 128;    // buf0 B
    const int bb1 = 32768 + bb0;                       // buf1 B

    f32x4 acc[8][4];
#pragma unroll
    for (int m = 0; m < 8; ++m)
#pragma unroll
        for (int n = 0; n < 4; ++n)
            acc[m][n] = (f32x4){0.f, 0.f, 0.f, 0.f};
    bf16x8 af[2][2];    // A frags for current quadrant (rewritten each phase-end)
    bf16x8 bfr[4][2];   // B frags for current tile (rewritten at P3/P7-end)

#define GLD16(SRC, LOFF)                                                       \
    __builtin_amdgcn_global_load_lds((const glb_char*)(SRC),                   \
                                     (lds_char*)(sm + (LOFF)), 16, 0, 0)
    // stage FULL A tile (both 128-row halves): 4 loads/wave
#define STAGE_A2(KT, BUF) do {                                                 \
        const int ra_ = (w << 4);                                              \
        GLD16(Abase + (size_t)(ra_ + lsub) * K_DIM + (KT) * BK,                \
              (BUF) * 32768 + ra_ * 128);                                      \
        GLD16(Abase + (size_t)(ra_ + 8 + lsub) * K_DIM + (KT) * BK,            \
              (BUF) * 32768 + (ra_ + 8) * 128);                                \
        GLD16(Abase + (size_t)(128 + ra_ + lsub) * K_DIM + (KT) * BK,          \
              (BUF) * 32768 + (128 + ra_) * 128);                              \
        GLD16(Abase + (size_t)(128 + ra_ + 8 + lsub) * K_DIM + (KT) * BK,      \
              (BUF) * 32768 + (128 + ra_ + 8) * 128);                          \
    } while (0)
    // stage one B half-tile (128 rows): 2 loads/wave
#define STAGE_B(KT, H, BUF) do {                                               \
        const int rb_ = (H) * 128 + (w << 4);                                  \
        GLD16(Wbase + (size_t)(rb_ + lsub) * K_DIM + (KT) * BK,                \
              65536 + (BUF) * 32768 + rb_ * 128);                              \
        GLD16(Wbase + (size_t)(rb_ + 8 + lsub) * K_DIM + (KT) * BK,            \
              65536 + (BUF) * 32768 + (rb_ + 8) * 128);                        \
    } while (0)

    // ds_read next quadrant's A frags into af (regs dead after this phase's MFMA)
#define RD_A(Q, ABASE) do {                                                    \
        _Pragma("unroll") for (int m2 = 0; m2 < 2; ++m2)                       \
        _Pragma("unroll") for (int kk = 0; kk < 2; ++kk)                       \
            af[m2][kk] = *(const bf16x8*)(sm + (ABASE) +                       \
                ((Q) * 32 + m2 * 16) * 128 + ((kk * 64 + kcb0) ^ fxor));       \
    } while (0)
#define RD_B(BBASE) do {                                                       \
        _Pragma("unroll") for (int n = 0; n < 4; ++n)                          \
        _Pragma("unroll") for (int kk = 0; kk < 2; ++kk)                       \
            bfr[n][kk] = *(const bf16x8*)(sm + (BBASE) +                       \
                (n * 16) * 128 + ((kk * 64 + kcb0) ^ fxor));                   \
    } while (0)

    // phase: [lgkm(0) | MFMA(Q) | reads-for-next | stage | gate | barrier]
#define PH(Q, READS, STAGES, GATE) do {                                        \
        asm volatile("s_waitcnt lgkmcnt(0)" ::: "memory");                     \
        __builtin_amdgcn_sched_barrier(0);                                     \
        __builtin_amdgcn_s_setprio(1);                                         \
        _Pragma("unroll") for (int m2 = 0; m2 < 2; ++m2)                       \
        _Pragma("unroll") for (int n = 0; n < 4; ++n)                          \
        _Pragma("unroll") for (int kk = 0; kk < 2; ++kk)                       \
            acc[(Q) * 2 + m2][n] = __builtin_amdgcn_mfma_f32_16x16x32_bf16(    \
                af[m2][kk], bfr[n][kk], acc[(Q) * 2 + m2][n], 0, 0, 0);        \
        __builtin_amdgcn_s_setprio(0);                                         \
        __builtin_amdgcn_sched_barrier(0);                                     \
        READS;                                                                 \
        STAGES;                                                                \
        GATE;                                                                  \
        __builtin_amdgcn_s_barrier();                                          \
        __builtin_amdgcn_sched_barrier(0);                                     \
    } while (0)

#define GATE2  asm volatile("s_waitcnt vmcnt(2)" ::: "memory")
#define GATE0v asm volatile("s_waitcnt vmcnt(0)" ::: "memory")
#define NOGATE do {} while (0)
#define NOOP   do {} while (0)

    // prologue: A(0)->buf0 (4), B(0)->buf0 (4), B(1)->buf1 (4)
    STAGE_A2(0, 0);
    STAGE_B(0, 0, 0); STAGE_B(0, 1, 0);
    STAGE_B(1, 0, 1); STAGE_B(1, 1, 1);
    asm volatile("s_waitcnt vmcnt(4)" ::: "memory");   // A(0),B(0) landed
    __builtin_amdgcn_s_barrier();
    __builtin_amdgcn_sched_barrier(0);
    RD_B(bb0);        // B(0) frags
    RD_A(0, ab0);     // Q0(0) frags   -> loop P0's lgkm(0) gates these

    for (int i = 0; i < NT / 2 - 1; ++i) {       // 15 steady iters
        const int t0 = 2 * i;
        // tile t0 (buf0)
        PH(0, RD_A(1, ab0),                  STAGE_A2(t0 + 1, 1),   NOGATE);
        PH(1, RD_A(2, ab0),                  NOOP,                  NOGATE);
        PH(2, RD_A(3, ab0),                  STAGE_B(t0 + 2, 0, 0), GATE2);
        PH(3, { RD_A(0, ab1); RD_B(bb1); },  STAGE_B(t0 + 2, 1, 0), NOGATE);
        // tile t0+1 (buf1)
        PH(0, RD_A(1, ab1),                  STAGE_A2(t0 + 2, 0),   NOGATE);
        PH(1, RD_A(2, ab1),                  NOOP,                  NOGATE);
        PH(2, RD_A(3, ab1),                  STAGE_B(t0 + 3, 0, 1), GATE2);
        PH(3, { RD_A(0, ab0); RD_B(bb0); },  STAGE_B(t0 + 3, 1, 1), NOGATE);
    }
    {   // peel: tiles NT-2 (buf0), NT-1 (buf1); no further staging
        PH(0, RD_A(1, ab0),                  STAGE_A2(NT - 1, 1),   NOGATE);
        PH(1, RD_A(2, ab0),                  NOOP,                  NOGATE);
        PH(2, RD_A(3, ab0),                  NOOP,                  GATE0v);
        PH(3, { RD_A(0, ab1); RD_B(bb1); },  NOOP,                  NOGATE);
        PH(0, RD_A(1, ab1),                  NOOP,                  NOGATE);
        PH(1, RD_A(2, ab1),                  NOOP,                  NOGATE);
        PH(2, RD_A(3, ab1),                  NOOP,                  NOGATE);
        PH(3, NOOP,                          NOOP,                  NOGATE);
    }
#undef NOOP
#undef NOGATE
#undef GATE0v
#undef GATE2
#undef PH
#undef RD_B
#undef RD_A
#undef STAGE_B
#undef STAGE_A2
#undef GLD16

    // epilogue: C/D layout col=lane&15, row=(lane>>4)*4+reg (R1-R5 validated)
    const size_t crow = (size_t)(bm * BM + wm * 128 + ((lane >> 4) << 2));
    const int    ccol = bn * BN + wn * 64 + (lane & 15);
    float* Cp = C + crow * N_DIM + ccol;
#pragma unroll
    for (int m = 0; m < 8; ++m)
#pragma unroll
        for (int j = 0; j < 4; ++j) {
            float* cr = Cp + (size_t)(m * 16 + j) * N_DIM;
#pragma unroll
            for (int n = 0; n < 4; ++n)
                cr[n * 16] = acc[m][n][j];
        }
}

// ---------------- fused fp32 fallback (ws too small; R1-validated) ----------
__global__ __launch_bounds__(256, 2)
void agmm_fused(const float* __restrict__ A, const float* __restrict__ W,
                float* __restrict__ C) {
    __shared__ __attribute__((aligned(16))) char sA[128 * 64 * 2];
    __shared__ __attribute__((aligned(16))) char sB[128 * 64 * 2];

    const int tid  = threadIdx.x;
    const int lane = tid & 63;
    const int wid  = tid >> 6;
    const int wm   = wid >> 1;
    const int wn   = wid & 1;

    const int nwg = (M_DIM / 128) * (N_DIM / 128);
    const int bid = blockIdx.x;
    const int swz = (bid & 7) * (nwg / 8) + (bid >> 3);
    const int bm  = swz >> 4;
    const int bn  = swz & 15;

    const int srow = tid >> 4;
    const int scol = (tid & 15) << 2;

    const float* Ap = A + (size_t)(bm * 128 + srow) * K_DIM + scol;
    const float* Wp = W + (size_t)(bn * 128 + srow) * K_DIM + scol;
    const int wbase = (srow * 128 + (scol << 1)) ^ ((srow & 7) << 4);

    const int lrow = lane & 15;
    const int lkb  = (lane >> 4) << 3;
    const int fxor = (lrow & 7) << 4;
    const int arow0 = (wm * 64 + lrow) * 128;
    const int brow0 = (wn * 64 + lrow) * 128;

    f32x4 acc[4][4];
#pragma unroll
    for (int m = 0; m < 4; ++m)
#pragma unroll
        for (int n = 0; n < 4; ++n)
            acc[m][n] = (f32x4){0.f, 0.f, 0.f, 0.f};

    float4 areg[8], breg[8];
#pragma unroll
    for (int p = 0; p < 8; ++p) {
        areg[p] = *reinterpret_cast<const float4*>(Ap + (size_t)p * 16 * K_DIM);
        breg[p] = *reinterpret_cast<const float4*>(Wp + (size_t)p * 16 * K_DIM);
    }

    for (int kt = 0; kt < NT; ++kt) {
        __syncthreads();
#pragma unroll
        for (int p = 0; p < 8; ++p) {
            ushort av[4] = {f2bf(areg[p].x), f2bf(areg[p].y),
                            f2bf(areg[p].z), f2bf(areg[p].w)};
            *reinterpret_cast<ushort4*>(sA + (wbase + p * 2048)) =
                *reinterpret_cast<ushort4*>(av);
            ushort bv[4] = {f2bf(breg[p].x), f2bf(breg[p].y),
                            f2bf(breg[p].z), f2bf(breg[p].w)};
            *reinterpret_cast<ushort4*>(sB + (wbase + p * 2048)) =
                *reinterpret_cast<ushort4*>(bv);
        }
        __syncthreads();

        if (kt + 1 < NT) {
            const float* ap = Ap + (size_t)(kt + 1) * BK;
            const float* wp = Wp + (size_t)(kt + 1) * BK;
#pragma unroll
            for (int p = 0; p < 8; ++p) {
                areg[p] = *reinterpret_cast<const float4*>(ap + (size_t)p * 16 * K_DIM);
                breg[p] = *reinterpret_cast<const float4*>(wp + (size_t)p * 16 * K_DIM);
            }
        }

#pragma unroll
        for (int kk = 0; kk < 2; ++kk) {
            const int kcb = (kk * 32 + lkb) * 2;
            bf16x8 af[4], bfv[4];
#pragma unroll
            for (int m = 0; m < 4; ++m)
                af[m] = *reinterpret_cast<const bf16x8*>(
                    sA + ((arow0 + m * 2048 + kcb) ^ fxor));
#pragma unroll
            for (int n = 0; n < 4; ++n)
                bfv[n] = *reinterpret_cast<const bf16x8*>(
                    sB + ((brow0 + n * 2048 + kcb) ^ fxor));
#pragma unroll
            for (int m = 0; m < 4; ++m)
#pragma unroll
                for (int n = 0; n < 4; ++n)
                    acc[m][n] = __builtin_amdgcn_mfma_f32_16x16x32_bf16(
                        af[m], bfv[n], acc[m][n], 0, 0, 0);
        }
    }

    const size_t crow = (size_t)(bm * 128 + wm * 64 + ((lane >> 4) << 2));
    const int    ccol = bn * 128 + wn * 64 + (lane & 15);
    float* Cp = C + crow * N_DIM + ccol;
#pragma unroll
    for (int m = 0; m < 4; ++m)
#pragma unroll
        for (int j = 0; j < 4; ++j) {
            float* cr = Cp + (size_t)(m * 16 + j) * N_DIM;
#pragma unroll
            for (int n = 0; n < 4; ++n)
                cr[n * 16] = acc[m][n][j];
        }
}

extern "C" void kernel_launch(void* const* d_in, const int* in_sizes, int n_in,
                              void* d_out, int out_size, void* d_ws, size_t ws_size,
                              hipStream_t stream) {
    const float* A  = (const float*)d_in[0];   // [8,4096,2048] fp32
    const float* Wt = (const float*)d_in[1];   // [2048,2048] fp32
    float* C = (float*)d_out;                  // [32768,2048] fp32

    const size_t needA = (size_t)M_DIM * K_DIM * 2;
    const size_t needW = (size_t)N_DIM * K_DIM * 2;

    if (ws_size >= needA + needW) {
        ushort* Abf = (ushort*)d_ws;
        ushort* Wbf = (ushort*)((char*)d_ws + needA);
        cvt_f32_bf16<<<dim3(2048), dim3(256), 0, stream>>>(A, Abf, (M_DIM * K_DIM) / 8);
        cvt_f32_bf16<<<dim3(2048), dim3(256), 0, stream>>>(Wt, Wbf, (N_DIM * K_DIM) / 8);
        agmm_8phase<<<dim3(NWG), dim3(512), 0, stream>>>(Abf, Wbf, C);
    } else {
        agmm_fused<<<dim3((M_DIM / 128) * (N_DIM / 128)), dim3(256), 0, stream>>>(A, Wt, C);
    }
}

// Round 7
// 339.860 us; speedup vs baseline: 1.0305x; 1.0305x over previous
//
#include <hip/hip_runtime.h>
#include <hip/hip_bf16.h>

// C[M,N] = A[M,K] @ W[N,K]^T ; M=32768, N=K=2048. fp32 in/out.
// R7: 256x256-tile 8-wave GEMM, ONE barrier / ONE gate / ONE sched-pin per
// K-tile. Rationale: within a K-tile there is NO cross-wave hazard (reads hit
// buf(t) published at tile entry; stages target buf(t+1) whose readers, tile
// t-1, finished before that same barrier; every ds_read's consumer MFMA is in
// the same tile body so lgkm waits retire reads pre-barrier). Compiler is free
// to interleave 24 ds_read_b128 | 8 global_load_lds | 64 MFMA per tile with
// its own fine-grained lgkmcnt. A-frags double-banked (afA/afB) so quadrant
// Q+1 reads overlap quadrant Q MFMA. Gate vmcnt(0) is pre-aged ~400-900 cyc
// (stages issued early in the tile) -> cheap drain.
// Tile boundary = [vmcnt(0) asm(memory)] [s_barrier] [sched_barrier(0)].

typedef __attribute__((ext_vector_type(8))) short bf16x8;
typedef __attribute__((ext_vector_type(4))) float f32x4;

#define M_DIM 32768
#define N_DIM 2048
#define K_DIM 2048
#define BM 256
#define BN 256
#define BK 64
#define NT (K_DIM / BK)              // 32
#define NBN (N_DIM / BN)             // 8
#define NWG ((M_DIM / BM) * NBN)     // 1024

typedef __attribute__((address_space(3))) char lds_char;
typedef __attribute__((address_space(1))) char glb_char;

__device__ __forceinline__ unsigned short f2bf(float f) {
    __bf16 b = (__bf16)f;   // RNE
    return __builtin_bit_cast(unsigned short, b);
}

// ---------------- fp32 -> bf16 convert (memory-bound, grid-stride) ----------
__global__ __launch_bounds__(256)
void cvt_f32_bf16(const float* __restrict__ src, ushort* __restrict__ dst, int n8) {
    const float4* s4 = (const float4*)src;
    int idx = blockIdx.x * blockDim.x + threadIdx.x;
    int stride = gridDim.x * blockDim.x;
    for (int i = idx; i < n8; i += stride) {
        float4 a = s4[2 * (size_t)i];
        float4 b = s4[2 * (size_t)i + 1];
        ushort r[8] = {f2bf(a.x), f2bf(a.y), f2bf(a.z), f2bf(a.w),
                       f2bf(b.x), f2bf(b.y), f2bf(b.z), f2bf(b.w)};
        *reinterpret_cast<uint4*>(dst + 8 * (size_t)i) =
            *reinterpret_cast<const uint4*>(r);
    }
}

// ---------------- 256^2 8-wave 1-barrier-per-K-tile bf16 GEMM ---------------
__global__ __launch_bounds__(512, 2)
void agmm_1bar(const ushort* __restrict__ A, const ushort* __restrict__ W,
               float* __restrict__ C) {
    // sA[buf]: buf*32768 ; sB[buf]: 65536 + buf*32768 (256r x 64c bf16, 128B rows)
    __shared__ __attribute__((aligned(16))) char sm[131072];

    const int tid  = threadIdx.x;
    const int lane = tid & 63;
    const int w    = tid >> 6;      // 0..7
    const int wm   = w >> 2;        // 0..1 -> 128-row half of A tile
    const int wn   = w & 3;         // 0..3 -> 64-col slice of B tile

    const int bid = blockIdx.x;
    const int swz = (bid & 7) * (NWG / 8) + (bid >> 3);  // bijective (NWG%8==0)
    const int bm  = swz >> 3;            // 0..127
    const int bn  = swz & (NBN - 1);     // 0..7

    // staging source pre-swizzle (linear LDS dest; read applies same XOR)
    const int lsub = lane >> 3;                       // row&7 at dest
    const int scol = ((lane & 7) ^ lsub) << 3;        // pre-swizzled col elems

    const ushort* Abase = A + (size_t)bm * BM * K_DIM + scol;
    const ushort* Wbase = W + (size_t)bn * BN * K_DIM + scol;

    const int lrow = lane & 15;
    const int fxor = (lrow & 7) << 4;
    const int kcb0 = (lane >> 4) << 4;    // 0,16,32,48 byte k-offset
    // per-lane swizzled k-offsets for kk=0,1 (fold row term at use site)
    const int offk0 = (0 + kcb0) ^ fxor;
    const int offk1 = (64 + kcb0) ^ fxor;

    const int abC = (wm * 128 + lrow) * 128;           // A row base (buf0)
    const int bbC = 65536 + (wn * 64 + lrow) * 128;    // B row base (buf0)

    f32x4 acc[8][4];
#pragma unroll
    for (int m = 0; m < 8; ++m)
#pragma unroll
        for (int n = 0; n < 4; ++n)
            acc[m][n] = (f32x4){0.f, 0.f, 0.f, 0.f};
    bf16x8 afA[2][2], afB[2][2];   // double-banked A frags (static-indexed)
    bf16x8 bfr[4][2];              // B frags, live for whole K-tile

#define GLD16(SRC, LOFF)                                                       \
    __builtin_amdgcn_global_load_lds((const glb_char*)(SRC),                   \
                                     (lds_char*)(sm + (LOFF)), 16, 0, 0)
    // stage FULL A tile (256 rows): 4 loads/wave; wave w covers rows 16w..16w+15
#define STAGE_A2(KT, BUF) do {                                                 \
        const int ra_ = (w << 4);                                              \
        GLD16(Abase + (size_t)(ra_ + lsub) * K_DIM + (KT) * BK,                \
              (BUF) * 32768 + ra_ * 128);                                      \
        GLD16(Abase + (size_t)(ra_ + 8 + lsub) * K_DIM + (KT) * BK,            \
              (BUF) * 32768 + (ra_ + 8) * 128);                                \
        GLD16(Abase + (size_t)(128 + ra_ + lsub) * K_DIM + (KT) * BK,          \
              (BUF) * 32768 + (128 + ra_) * 128);                              \
        GLD16(Abase + (size_t)(128 + ra_ + 8 + lsub) * K_DIM + (KT) * BK,      \
              (BUF) * 32768 + (128 + ra_ + 8) * 128);                          \
    } while (0)
    // stage one B half-tile (128 rows): 2 loads/wave
#define STAGE_B(KT, H, BUF) do {                                               \
        const int rb_ = (H) * 128 + (w << 4);                                  \
        GLD16(Wbase + (size_t)(rb_ + lsub) * K_DIM + (KT) * BK,                \
              65536 + (BUF) * 32768 + rb_ * 128);                              \
        GLD16(Wbase + (size_t)(rb_ + 8 + lsub) * K_DIM + (KT) * BK,            \
              65536 + (BUF) * 32768 + (rb_ + 8) * 128);                        \
    } while (0)

#define RD_A(Q, ABASE, DST) do {                                               \
        _Pragma("unroll") for (int m2 = 0; m2 < 2; ++m2) {                     \
            DST[m2][0] = *(const bf16x8*)(sm + (ABASE) +                       \
                ((Q) * 32 + m2 * 16) * 128 + offk0);                           \
            DST[m2][1] = *(const bf16x8*)(sm + (ABASE) +                       \
                ((Q) * 32 + m2 * 16) * 128 + offk1);                           \
        }                                                                      \
    } while (0)
#define RD_B(BBASE) do {                                                       \
        _Pragma("unroll") for (int n = 0; n < 4; ++n) {                        \
            bfr[n][0] = *(const bf16x8*)(sm + (BBASE) + (n * 16) * 128 + offk0);\
            bfr[n][1] = *(const bf16x8*)(sm + (BBASE) + (n * 16) * 128 + offk1);\
        }                                                                      \
    } while (0)
#define MFMA_Q(Q, AF) do {                                                     \
        __builtin_amdgcn_s_setprio(1);                                         \
        _Pragma("unroll") for (int m2 = 0; m2 < 2; ++m2)                       \
        _Pragma("unroll") for (int n = 0; n < 4; ++n)                          \
        _Pragma("unroll") for (int kk = 0; kk < 2; ++kk)                       \
            acc[(Q) * 2 + m2][n] = __builtin_amdgcn_mfma_f32_16x16x32_bf16(    \
                AF[m2][kk], bfr[n][kk], acc[(Q) * 2 + m2][n], 0, 0, 0);        \
        __builtin_amdgcn_s_setprio(0);                                         \
    } while (0)

#define TILE_BOUNDARY do {                                                     \
        asm volatile("s_waitcnt vmcnt(0)" ::: "memory");                       \
        __builtin_amdgcn_s_barrier();                                          \
        __builtin_amdgcn_sched_barrier(0);                                     \
    } while (0)

    // prologue: stage tile 0 into buf0 (8 loads), publish
    STAGE_A2(0, 0);
    STAGE_B(0, 0, 0);
    STAGE_B(0, 1, 0);
    TILE_BOUNDARY;

    for (int t = 0; t < NT - 1; ++t) {
        const int cur   = t & 1;
        const int nxt   = cur ^ 1;
        const int abase = cur * 32768 + abC;
        const int bbase = cur * 32768 + bbC;
        // tile body: compiler-scheduled reads | stages | MFMA (no intra pins)
        RD_B(bbase);
        RD_A(0, abase, afA);
        RD_A(1, abase, afB);
        STAGE_A2(t + 1, nxt);
        MFMA_Q(0, afA);
        RD_A(2, abase, afA);
        STAGE_B(t + 1, 0, nxt);
        MFMA_Q(1, afB);
        RD_A(3, abase, afB);
        STAGE_B(t + 1, 1, nxt);
        MFMA_Q(2, afA);
        MFMA_Q(3, afB);
        TILE_BOUNDARY;   // pre-aged drain of the 8 stage loads + publish
    }
    {   // last tile (buf parity (NT-1)&1 = 1): no staging, no trailing barrier
        const int abase = 32768 + abC;
        const int bbase = 32768 + bbC;
        RD_B(bbase);
        RD_A(0, abase, afA);
        RD_A(1, abase, afB);
        MFMA_Q(0, afA);
        RD_A(2, abase, afA);
        MFMA_Q(1, afB);
        RD_A(3, abase, afB);
        MFMA_Q(2, afA);
        MFMA_Q(3, afB);
    }
#undef TILE_BOUNDARY
#undef MFMA_Q
#undef RD_B
#undef RD_A
#undef STAGE_B
#undef STAGE_A2
#undef GLD16

    // epilogue: C/D layout col=lane&15, row=(lane>>4)*4+reg (R1-R6 validated)
    const size_t crow = (size_t)(bm * BM + wm * 128 + ((lane >> 4) << 2));
    const int    ccol = bn * BN + wn * 64 + (lane & 15);
    float* Cp = C + crow * N_DIM + ccol;
#pragma unroll
    for (int m = 0; m < 8; ++m)
#pragma unroll
        for (int j = 0; j < 4; ++j) {
            float* cr = Cp + (size_t)(m * 16 + j) * N_DIM;
#pragma unroll
            for (int n = 0; n < 4; ++n)
                cr[n * 16] = acc[m][n][j];
        }
}

// ---------------- fused fp32 fallback (ws too small; R1-validated) ----------
__global__ __launch_bounds__(256, 2)
void agmm_fused(const float* __restrict__ A, const float* __restrict__ W,
                float* __restrict__ C) {
    __shared__ __attribute__((aligned(16))) char sA[128 * 64 * 2];
    __shared__ __attribute__((aligned(16))) char sB[128 * 64 * 2];

    const int tid  = threadIdx.x;
    const int lane = tid & 63;
    const int wid  = tid >> 6;
    const int wm   = wid >> 1;
    const int wn   = wid & 1;

    const int nwg = (M_DIM / 128) * (N_DIM / 128);
    const int bid = blockIdx.x;
    const int swz = (bid & 7) * (nwg / 8) + (bid >> 3);
    const int bm  = swz >> 4;
    const int bn  = swz & 15;

    const int srow = tid >> 4;
    const int scol = (tid & 15) << 2;

    const float* Ap = A + (size_t)(bm * 128 + srow) * K_DIM + scol;
    const float* Wp = W + (size_t)(bn * 128 + srow) * K_DIM + scol;
    const int wbase = (srow * 128 + (scol << 1)) ^ ((srow & 7) << 4);

    const int lrow = lane & 15;
    const int lkb  = (lane >> 4) << 3;
    const int fxor = (lrow & 7) << 4;
    const int arow0 = (wm * 64 + lrow) * 128;
    const int brow0 = (wn * 64 + lrow) * 128;

    f32x4 acc[4][4];
#pragma unroll
    for (int m = 0; m < 4; ++m)
#pragma unroll
        for (int n = 0; n < 4; ++n)
            acc[m][n] = (f32x4){0.f, 0.f, 0.f, 0.f};

    float4 areg[8], breg[8];
#pragma unroll
    for (int p = 0; p < 8; ++p) {
        areg[p] = *reinterpret_cast<const float4*>(Ap + (size_t)p * 16 * K_DIM);
        breg[p] = *reinterpret_cast<const float4*>(Wp + (size_t)p * 16 * K_DIM);
    }

    for (int kt = 0; kt < NT; ++kt) {
        __syncthreads();
#pragma unroll
        for (int p = 0; p < 8; ++p) {
            ushort av[4] = {f2bf(areg[p].x), f2bf(areg[p].y),
                            f2bf(areg[p].z), f2bf(areg[p].w)};
            *reinterpret_cast<ushort4*>(sA + (wbase + p * 2048)) =
                *reinterpret_cast<ushort4*>(av);
            ushort bv[4] = {f2bf(breg[p].x), f2bf(breg[p].y),
                            f2bf(breg[p].z), f2bf(breg[p].w)};
            *reinterpret_cast<ushort4*>(sB + (wbase + p * 2048)) =
                *reinterpret_cast<ushort4*>(bv);
        }
        __syncthreads();

        if (kt + 1 < NT) {
            const float* ap = Ap + (size_t)(kt + 1) * BK;
            const float* wp = Wp + (size_t)(kt + 1) * BK;
#pragma unroll
            for (int p = 0; p < 8; ++p) {
                areg[p] = *reinterpret_cast<const float4*>(ap + (size_t)p * 16 * K_DIM);
                breg[p] = *reinterpret_cast<const float4*>(wp + (size_t)p * 16 * K_DIM);
            }
        }

#pragma unroll
        for (int kk = 0; kk < 2; ++kk) {
            const int kcb = (kk * 32 + lkb) * 2;
            bf16x8 af[4], bfv[4];
#pragma unroll
            for (int m = 0; m < 4; ++m)
                af[m] = *reinterpret_cast<const bf16x8*>(
                    sA + ((arow0 + m * 2048 + kcb) ^ fxor));
#pragma unroll
            for (int n = 0; n < 4; ++n)
                bfv[n] = *reinterpret_cast<const bf16x8*>(
                    sB + ((brow0 + n * 2048 + kcb) ^ fxor));
#pragma unroll
            for (int m = 0; m < 4; ++m)
#pragma unroll
                for (int n = 0; n < 4; ++n)
                    acc[m][n] = __builtin_amdgcn_mfma_f32_16x16x32_bf16(
                        af[m], bfv[n], acc[m][n], 0, 0, 0);
        }
    }

    const size_t crow = (size_t)(bm * 128 + wm * 64 + ((lane >> 4) << 2));
    const int    ccol = bn * 128 + wn * 64 + (lane & 15);
    float* Cp = C + crow * N_DIM + ccol;
#pragma unroll
    for (int m = 0; m < 4; ++m)
#pragma unroll
        for (int j = 0; j < 4; ++j) {
            float* cr = Cp + (size_t)(m * 16 + j) * N_DIM;
#pragma unroll
            for (int n = 0; n < 4; ++n)
                cr[n * 16] = acc[m][n][j];
        }
}

extern "C" void kernel_launch(void* const* d_in, const int* in_sizes, int n_in,
                              void* d_out, int out_size, void* d_ws, size_t ws_size,
                              hipStream_t stream) {
    const float* A  = (const float*)d_in[0];   // [8,4096,2048] fp32
    const float* Wt = (const float*)d_in[1];   // [2048,2048] fp32
    float* C = (float*)d_out;                  // [32768,2048] fp32

    const size_t needA = (size_t)M_DIM * K_DIM * 2;
    const size_t needW = (size_t)N_DIM * K_DIM * 2;

    if (ws_size >= needA + needW) {
        ushort* Abf = (ushort*)d_ws;
        ushort* Wbf = (ushort*)((char*)d_ws + needA);
        cvt_f32_bf16<<<dim3(2048), dim3(256), 0, stream>>>(A, Abf, (M_DIM * K_DIM) / 8);
        cvt_f32_bf16<<<dim3(2048), dim3(256), 0, stream>>>(Wt, Wbf, (N_DIM * K_DIM) / 8);
        agmm_1bar<<<dim3(NWG), dim3(512), 0, stream>>>(Abf, Wbf, C);
    } else {
        agmm_fused<<<dim3((M_DIM / 128) * (N_DIM / 128)), dim3(256), 0, stream>>>(A, Wt, C);
    }
}